// Round 12
// baseline (1260.452 us; speedup 1.0000x reference)
//
#include <hip/hip_runtime.h>
#include <math.h>

#define N_NODES 50000
#define N_EDGES 800000
#define G_GRAPHS 512
#define H_DIM 256
#define NF_DIM 32
#define EF_DIM 16
#define L_LAYERS 4
#define BN_EPS 1e-5f

typedef __bf16 bf16_t;
typedef __attribute__((ext_vector_type(8))) __bf16 bf16x8;
typedef __attribute__((ext_vector_type(4))) float f32x4;
typedef _Float16 f16_t;
typedef __attribute__((ext_vector_type(2))) _Float16 f16x2;
typedef __attribute__((ext_vector_type(8))) _Float16 f16x8;

union f16x8_pairs {
  f16x8 v;
  f16x2 p[4];
};

// ---------------- hb = bf16(x @ Win + bin) ---------------------------------
__global__ __launch_bounds__(256) void k_init_h(
    const float* __restrict__ x, const float* __restrict__ Win,
    const float* __restrict__ bin, bf16_t* __restrict__ hb) {
  int row = blockIdx.x;
  int c = threadIdx.x;
  __shared__ float xs[NF_DIM];
  if (threadIdx.x < NF_DIM) xs[threadIdx.x] = x[(size_t)row * NF_DIM + threadIdx.x];
  __syncthreads();
  float acc = bin[c];
#pragma unroll
  for (int k = 0; k < NF_DIM; ++k) acc += xs[k] * Win[k * H_DIM + c];
  hb[(size_t)row * H_DIM + c] = (bf16_t)acc;
}

// ---------------- weight transpose + bf16 cast (both W1,W2 in one grid) ----
__global__ __launch_bounds__(256) void k_prepW(
    const float* __restrict__ Wl1, const float* __restrict__ Wl2,
    bf16_t* __restrict__ Wt1, bf16_t* __restrict__ Wt2) {
  int n = blockIdx.x;
  int ly = blockIdx.y;  // 0..7
  int k = threadIdx.x;
  const float* W = (ly < L_LAYERS) ? Wl1 : Wl2;
  bf16_t* Wt = (ly < L_LAYERS) ? Wt1 : Wt2;
  int l = ly & 3;
  Wt[(size_t)l * 65536 + n * 256 + k] = (bf16_t)W[(size_t)l * 65536 + k * 256 + n];
}

// ---------------- CSR build ------------------------------------------------
__global__ __launch_bounds__(256) void k_deg(
    const int* __restrict__ dsts, int* __restrict__ deg) {
  int e = blockIdx.x * 256 + threadIdx.x;
  if (e < N_EDGES) atomicAdd(&deg[dsts[e]], 1);
}

#define SCAN_B 512
__global__ __launch_bounds__(SCAN_B) void k_scan1(
    const int* __restrict__ deg, int* __restrict__ incl, int* __restrict__ bsum) {
  __shared__ int s[SCAN_B];
  int gidx = blockIdx.x * SCAN_B + threadIdx.x;
  int v = (gidx < N_NODES) ? deg[gidx] : 0;
  s[threadIdx.x] = v;
  __syncthreads();
  for (int off = 1; off < SCAN_B; off <<= 1) {
    int t = (threadIdx.x >= off) ? s[threadIdx.x - off] : 0;
    __syncthreads();
    s[threadIdx.x] += t;
    __syncthreads();
  }
  if (gidx < N_NODES) incl[gidx] = s[threadIdx.x];
  if (threadIdx.x == SCAN_B - 1) bsum[blockIdx.x] = s[SCAN_B - 1];
}

__global__ void k_scan2(int* __restrict__ bsum, int nb) {
  if (threadIdx.x == 0 && blockIdx.x == 0) {
    int acc = 0;
    for (int i = 0; i < nb; ++i) { int t = bsum[i]; bsum[i] = acc; acc += t; }
  }
}

__global__ __launch_bounds__(SCAN_B) void k_scan3(
    const int* __restrict__ incl, const int* __restrict__ deg,
    const int* __restrict__ bsum, int* __restrict__ off) {
  int gidx = blockIdx.x * SCAN_B + threadIdx.x;
  if (gidx < N_NODES) off[gidx] = incl[gidx] - deg[gidx] + bsum[blockIdx.x];
  if (gidx == 0) off[N_NODES] = N_EDGES;
}

// scatter + direct ea->f16 reorder (no eid pass)
__global__ __launch_bounds__(256) void k_scatter(
    const int* __restrict__ srcs, const int* __restrict__ dsts,
    const int* __restrict__ off, int* __restrict__ fill,
    int* __restrict__ src_csr, const float* __restrict__ ea,
    f16_t* __restrict__ eac) {
  int e = blockIdx.x * 256 + threadIdx.x;
  if (e < N_EDGES) {
    int d = dsts[e];
    int pos = atomicAdd(&fill[d], 1);
    int idx = off[d] + pos;
    src_csr[idx] = srcs[e];
    const f32x4* p = (const f32x4*)(ea + (size_t)e * EF_DIM);
    f32x4 v0 = p[0], v1 = p[1], v2 = p[2], v3 = p[3];
    f16x8 o0, o1;
    o0[0] = (f16_t)v0.x; o0[1] = (f16_t)v0.y; o0[2] = (f16_t)v0.z; o0[3] = (f16_t)v0.w;
    o0[4] = (f16_t)v1.x; o0[5] = (f16_t)v1.y; o0[6] = (f16_t)v1.z; o0[7] = (f16_t)v1.w;
    o1[0] = (f16_t)v2.x; o1[1] = (f16_t)v2.y; o1[2] = (f16_t)v2.z; o1[3] = (f16_t)v2.w;
    o1[4] = (f16_t)v3.x; o1[5] = (f16_t)v3.y; o1[6] = (f16_t)v3.z; o1[7] = (f16_t)v3.w;
    f16x8* dst = (f16x8*)(eac + (size_t)idx * EF_DIM);
    dst[0] = o0;
    dst[1] = o1;
  }
}

// ---------------- fused layer: aggregation -> LDS -> 2xGEMM -> hbn ---------
// block = 64 rows, 512 threads. Phase 1: 4 groups x 128 threads aggregate
// 16 rows each into LDS buf (t0, bf16). Phase 2: GEMM1 (t1 = relu(t0@W1+b1))
// overwrites buf. Phase 3: GEMM2 + bn/relu/residual -> hbn. hb ping-pong
// (read hbp / write hbn) removes the aggr<->mlp global sync hazard.
#define FM 64
#define BSTR 264  // bf16 elems per LDS row (256 + 8 pad)

__device__ __forceinline__ void edge_dot2(const f16_t* __restrict__ eac,
                                          size_t i, const f16x2* __restrict__ w0,
                                          const f16x2* __restrict__ w1,
                                          float& m0, float& m1) {
  const f16x8* pp = (const f16x8*)(eac + i * EF_DIM);
  f16x8_pairs u0, u1;
  u0.v = pp[0];
  u1.v = pp[1];
#pragma unroll
  for (int j = 0; j < 4; ++j) {
    m0 = __builtin_amdgcn_fdot2(u0.p[j], w0[j], m0, false);
    m1 = __builtin_amdgcn_fdot2(u0.p[j], w1[j], m1, false);
  }
#pragma unroll
  for (int j = 0; j < 4; ++j) {
    m0 = __builtin_amdgcn_fdot2(u1.p[j], w0[j + 4], m0, false);
    m1 = __builtin_amdgcn_fdot2(u1.p[j], w1[j + 4], m1, false);
  }
}

__global__ __launch_bounds__(512, 4) void k_layer(
    const int* __restrict__ off, const int* __restrict__ src_csr,
    const f16_t* __restrict__ eac, const bf16_t* __restrict__ hbp,
    const float* __restrict__ We, const float* __restrict__ be,
    const bf16_t* __restrict__ W1t, const bf16_t* __restrict__ W2t,
    const float* __restrict__ b1, const float* __restrict__ b2,
    const float* __restrict__ bnw, const float* __restrict__ bnb,
    const float* __restrict__ bnm, const float* __restrict__ bnv,
    bf16_t* __restrict__ hbn) {
  __shared__ bf16_t buf[FM * BSTR];
  const int tid = threadIdx.x;
  const int bm = blockIdx.x * FM;

  // ---------- phase 1: aggregation of 64 rows into LDS buf ----------
  {
    const int grp = tid >> 7;   // 0..3
    const int gt = tid & 127;   // col-pair thread
    const int c0 = gt * 2;
    f16x2 w0[8], w1[8];
#pragma unroll
    for (int j = 0; j < 8; ++j) {
      f16x2 t0, t1;
      t0[0] = (f16_t)We[(2 * j) * H_DIM + c0];
      t0[1] = (f16_t)We[(2 * j + 1) * H_DIM + c0];
      t1[0] = (f16_t)We[(2 * j) * H_DIM + c0 + 1];
      t1[1] = (f16_t)We[(2 * j + 1) * H_DIM + c0 + 1];
      w0[j] = t0;
      w1[j] = t1;
    }
    const float be0 = be[c0], be1 = be[c0 + 1];
    const unsigned* __restrict__ hb32 = (const unsigned*)hbp;
    for (int r = 0; r < 16; ++r) {
      const int lrow = grp * 16 + r;
      const int n = bm + lrow;
      unsigned outv = 0u;
      if (n < N_NODES) {
        const int s0 = off[n], s1 = off[n + 1];
        float acc0 = 0.f, acc1 = 0.f;
        int i = s0;
        for (; i + 4 <= s1; i += 4) {
          int sA = src_csr[i], sB = src_csr[i + 1];
          int sC = src_csr[i + 2], sD = src_csr[i + 3];
          unsigned uA = hb32[(unsigned)sA * 128u + gt];
          unsigned uB = hb32[(unsigned)sB * 128u + gt];
          unsigned uC = hb32[(unsigned)sC * 128u + gt];
          unsigned uD = hb32[(unsigned)sD * 128u + gt];
          float mA0 = be0, mA1 = be1, mB0 = be0, mB1 = be1;
          float mC0 = be0, mC1 = be1, mD0 = be0, mD1 = be1;
          edge_dot2(eac, (size_t)i, w0, w1, mA0, mA1);
          edge_dot2(eac, (size_t)i + 1, w0, w1, mB0, mB1);
          edge_dot2(eac, (size_t)i + 2, w0, w1, mC0, mC1);
          edge_dot2(eac, (size_t)i + 3, w0, w1, mD0, mD1);
          acc0 += fmaxf(mA0 + __uint_as_float(uA << 16), 0.f) +
                  fmaxf(mB0 + __uint_as_float(uB << 16), 0.f) +
                  fmaxf(mC0 + __uint_as_float(uC << 16), 0.f) +
                  fmaxf(mD0 + __uint_as_float(uD << 16), 0.f);
          acc1 += fmaxf(mA1 + __uint_as_float(uA & 0xFFFF0000u), 0.f) +
                  fmaxf(mB1 + __uint_as_float(uB & 0xFFFF0000u), 0.f) +
                  fmaxf(mC1 + __uint_as_float(uC & 0xFFFF0000u), 0.f) +
                  fmaxf(mD1 + __uint_as_float(uD & 0xFFFF0000u), 0.f);
        }
        for (; i < s1; ++i) {
          int s = src_csr[i];
          unsigned u = hb32[(unsigned)s * 128u + gt];
          float m0 = be0, m1 = be1;
          edge_dot2(eac, (size_t)i, w0, w1, m0, m1);
          acc0 += fmaxf(m0 + __uint_as_float(u << 16), 0.f);
          acc1 += fmaxf(m1 + __uint_as_float(u & 0xFFFF0000u), 0.f);
        }
        unsigned hu = hb32[(size_t)n * 128 + gt];
        float h0 = __uint_as_float(hu << 16);
        float h1 = __uint_as_float(hu & 0xFFFF0000u);
        union { bf16_t b[2]; unsigned u; } pk;
        pk.b[0] = (bf16_t)(h0 + acc0);
        pk.b[1] = (bf16_t)(h1 + acc1);
        outv = pk.u;
      }
      ((unsigned*)(buf + lrow * BSTR))[gt] = outv;
    }
  }
  __syncthreads();

  // ---------- phase 2: GEMM1 t1 = relu(t0 @ W1 + b1) ----------
  const int lane = tid & 63;
  const int wv = tid >> 6;         // 0..7
  const int wm = (wv & 1) * 32;    // 32-row group
  const int wn = (wv >> 1) * 64;   // 64-col group
  const int l15 = lane & 15;
  const int kg = lane >> 4;
  f32x4 acc[2][4];
#pragma unroll
  for (int m = 0; m < 2; ++m)
#pragma unroll
    for (int n = 0; n < 4; ++n) acc[m][n] = (f32x4){0.f, 0.f, 0.f, 0.f};
  for (int ks = 0; ks < 8; ++ks) {
    const int k0 = ks * 32;
    bf16x8 af[2], bfr[4];
#pragma unroll
    for (int m = 0; m < 2; ++m)
      af[m] = *(const bf16x8*)&buf[(wm + m * 16 + l15) * BSTR + k0 + kg * 8];
#pragma unroll
    for (int n = 0; n < 4; ++n)
      bfr[n] = *(const bf16x8*)&W1t[(size_t)(wn + n * 16 + l15) * H_DIM + k0 + kg * 8];
#pragma unroll
    for (int m = 0; m < 2; ++m)
#pragma unroll
      for (int n = 0; n < 4; ++n)
        acc[m][n] =
            __builtin_amdgcn_mfma_f32_16x16x32_bf16(af[m], bfr[n], acc[m][n], 0, 0, 0);
  }
  __syncthreads();  // all reads of t0 done; t1 overwrites buf
#pragma unroll
  for (int m = 0; m < 2; ++m) {
    int rl0 = wm + m * 16 + kg * 4;
#pragma unroll
    for (int n = 0; n < 4; ++n) {
      int col = wn + n * 16 + l15;
      float bi = b1[col];
#pragma unroll
      for (int r = 0; r < 4; ++r)
        buf[(rl0 + r) * BSTR + col] = (bf16_t)fmaxf(acc[m][n][r] + bi, 0.f);
    }
  }
  __syncthreads();

  // ---------- phase 3: GEMM2 + bn/relu/residual -> hbn ----------
#pragma unroll
  for (int m = 0; m < 2; ++m)
#pragma unroll
    for (int n = 0; n < 4; ++n) acc[m][n] = (f32x4){0.f, 0.f, 0.f, 0.f};
  for (int ks = 0; ks < 8; ++ks) {
    const int k0 = ks * 32;
    bf16x8 af[2], bfr[4];
#pragma unroll
    for (int m = 0; m < 2; ++m)
      af[m] = *(const bf16x8*)&buf[(wm + m * 16 + l15) * BSTR + k0 + kg * 8];
#pragma unroll
    for (int n = 0; n < 4; ++n)
      bfr[n] = *(const bf16x8*)&W2t[(size_t)(wn + n * 16 + l15) * H_DIM + k0 + kg * 8];
#pragma unroll
    for (int m = 0; m < 2; ++m)
#pragma unroll
      for (int n = 0; n < 4; ++n)
        acc[m][n] =
            __builtin_amdgcn_mfma_f32_16x16x32_bf16(af[m], bfr[n], acc[m][n], 0, 0, 0);
  }
#pragma unroll
  for (int m = 0; m < 2; ++m) {
    int row0 = bm + wm + m * 16 + kg * 4;
#pragma unroll
    for (int n = 0; n < 4; ++n) {
      int col = wn + n * 16 + l15;
      float bi = b2[col];
      float sc = bnw[col] * rsqrtf(bnv[col] + BN_EPS);
      float mu = bnm[col];
      float sb = bnb[col];
#pragma unroll
      for (int r = 0; r < 4; ++r) {
        int rr = row0 + r;
        if (rr < N_NODES) {
          float v = (acc[m][n][r] + bi - mu) * sc + sb;
          size_t o = (size_t)rr * H_DIM + col;
          float old = (float)hbp[o];
          hbn[o] = (bf16_t)(old + fmaxf(v, 0.f));
        }
      }
    }
  }
}

// ---------------- pooling: g[b] = sum over nodes (batch sorted, bf16 in) ---
__global__ __launch_bounds__(512) void k_pool(
    const int* __restrict__ batch, const bf16_t* __restrict__ hb,
    float* __restrict__ g, float* __restrict__ out_g) {
  int gid = blockIdx.x;
  int cp = threadIdx.x & 127;  // col pair
  int rl = threadIdx.x >> 7;   // 0..3
  int lo = 0, hi = N_NODES;
  while (lo < hi) { int mid = (lo + hi) >> 1; if (batch[mid] < gid) lo = mid + 1; else hi = mid; }
  int start = lo;
  int lo2 = start, hi2 = N_NODES;
  while (lo2 < hi2) { int mid = (lo2 + hi2) >> 1; if (batch[mid] < gid + 1) lo2 = mid + 1; else hi2 = mid; }
  int end = lo2;
  const unsigned* hb32 = (const unsigned*)hb;
  float a0 = 0.f, a1 = 0.f;
  for (int n = start + rl; n < end; n += 4) {
    unsigned u = hb32[(size_t)n * 128 + cp];
    a0 += __uint_as_float(u << 16);
    a1 += __uint_as_float(u & 0xFFFF0000u);
  }
  __shared__ float red[4][H_DIM];
  red[rl][2 * cp] = a0;
  red[rl][2 * cp + 1] = a1;
  __syncthreads();
  if (rl == 0) {
    float s0 = red[0][2 * cp] + red[1][2 * cp] + red[2][2 * cp] + red[3][2 * cp];
    float s1 = red[0][2 * cp + 1] + red[1][2 * cp + 1] + red[2][2 * cp + 1] + red[3][2 * cp + 1];
    g[(size_t)gid * H_DIM + 2 * cp] = s0;
    g[(size_t)gid * H_DIM + 2 * cp + 1] = s1;
    out_g[(size_t)gid * H_DIM + 2 * cp] = s0;
    out_g[(size_t)gid * H_DIM + 2 * cp + 1] = s1;
  }
}

// ---------------- fused tail: z / edl heads, one block per graph -----------
__device__ __forceinline__ float softplusf(float x) {
  return fmaxf(x, 0.f) + log1pf(expf(-fabsf(x)));
}

__global__ __launch_bounds__(256) void k_tail(
    const float* __restrict__ g, const float* __restrict__ gf,
    const float* __restrict__ Wp1, const float* __restrict__ bp1,
    const float* __restrict__ Wp2, const float* __restrict__ bp2,
    const float* __restrict__ Wf1, const float* __restrict__ bf1,
    const float* __restrict__ Wf2, const float* __restrict__ bf2,
    const float* __restrict__ Wh, const float* __restrict__ bh,
    float* __restrict__ out) {
  int gid = blockIdx.x;
  int c = threadIdx.x;
  __shared__ float gc[H_DIM + NF_DIM];
  __shared__ float z1[128];
  __shared__ float q1[H_DIM];
  __shared__ float q2[128];
  gc[c] = g[(size_t)gid * H_DIM + c];
  if (c < NF_DIM) gc[H_DIM + c] = gf[(size_t)gid * NF_DIM + c];
  __syncthreads();
  float aq = bf1[c];
#pragma unroll 8
  for (int k = 0; k < H_DIM + NF_DIM; ++k) aq += gc[k] * Wf1[k * H_DIM + c];
  if (c < 128) {
    float a = bp1[c];
#pragma unroll 8
    for (int k = 0; k < H_DIM; ++k) a += gc[k] * Wp1[k * 128 + c];
    z1[c] = fmaxf(a, 0.f);
  }
  q1[c] = fmaxf(aq, 0.f);
  __syncthreads();
  if (c < 64) {
    float a = bp2[c];
#pragma unroll 8
    for (int k = 0; k < 128; ++k) a += z1[k] * Wp2[k * 64 + c];
    float ss = a * a;
#pragma unroll
    for (int o = 32; o; o >>= 1) ss += __shfl_xor(ss, o);
    float nrm = fmaxf(sqrtf(ss), 1e-12f);
    out[2048 + (size_t)gid * 64 + c] = a / nrm;
  }
  if (c < 128) {
    float a = bf2[c];
#pragma unroll 8
    for (int k = 0; k < H_DIM; ++k) a += q1[k] * Wf2[k * 128 + c];
    q2[c] = fmaxf(a, 0.f);
  }
  __syncthreads();
  if (c < 4) {
    float a = bh[c];
#pragma unroll 8
    for (int k = 0; k < 128; ++k) a += q2[k] * Wh[k * 4 + c];
    float v;
    if (c == 0) v = a;
    else if (c == 2) v = softplusf(a) + 1.f + 1e-6f;
    else v = softplusf(a) + 1e-6f;
    out[(size_t)gid * 4 + c] = v;
  }
}

extern "C" void kernel_launch(void* const* d_in, const int* in_sizes, int n_in,
                              void* d_out, int out_size, void* d_ws, size_t ws_size,
                              hipStream_t stream) {
  const float* x     = (const float*)d_in[0];
  const int*   ei    = (const int*)d_in[1];
  const float* ea    = (const float*)d_in[2];
  const int*   batch = (const int*)d_in[3];
  const float* gf    = (const float*)d_in[4];
  const float* Win   = (const float*)d_in[5];
  const float* bin   = (const float*)d_in[6];
  const float* We    = (const float*)d_in[7];
  const float* be    = (const float*)d_in[8];
  const float* Wl1   = (const float*)d_in[9];
  const float* bl1   = (const float*)d_in[10];
  const float* Wl2   = (const float*)d_in[11];
  const float* bl2   = (const float*)d_in[12];
  const float* bnw   = (const float*)d_in[13];
  const float* bnb   = (const float*)d_in[14];
  const float* bnm   = (const float*)d_in[15];
  const float* bnv   = (const float*)d_in[16];
  const float* Wp1   = (const float*)d_in[17];
  const float* bp1   = (const float*)d_in[18];
  const float* Wp2   = (const float*)d_in[19];
  const float* bp2   = (const float*)d_in[20];
  const float* Wf1   = (const float*)d_in[21];
  const float* bf1   = (const float*)d_in[22];
  const float* Wf2   = (const float*)d_in[23];
  const float* bf2   = (const float*)d_in[24];
  const float* Wh    = (const float*)d_in[25];
  const float* bh    = (const float*)d_in[26];
  float* out = (float*)d_out;

  const int* srcs = ei;
  const int* dsts = ei + N_EDGES;

  const size_t NH = (size_t)N_NODES * H_DIM;
  float* g   = (float*)d_ws;
  f16_t* eac = (f16_t*)(g + (size_t)G_GRAPHS * H_DIM);  // N_EDGES*16 f16
  bf16_t* hb0 = (bf16_t*)(eac + (size_t)N_EDGES * EF_DIM);
  bf16_t* hb1 = hb0 + NH;
  bf16_t* Wt1 = hb1 + NH;                         // 4*65536
  bf16_t* Wt2 = Wt1 + (size_t)L_LAYERS * 65536;
  int* deg  = (int*)(Wt2 + (size_t)L_LAYERS * 65536);
  int* fill = deg + N_NODES;
  int* incl = fill + N_NODES;
  int* off  = incl + N_NODES;       // N_NODES + 1
  int* bsum = off + N_NODES + 1;    // 128
  int* src_csr = bsum + 128;        // N_EDGES

  // ---- one-time prep: CSR build (+ea reorder fused) + weight cast + proj --
  hipMemsetAsync(deg, 0, N_NODES * sizeof(int), stream);
  hipMemsetAsync(fill, 0, N_NODES * sizeof(int), stream);
  const int nscan = (N_NODES + SCAN_B - 1) / SCAN_B;
  k_deg<<<(N_EDGES + 255) / 256, 256, 0, stream>>>(dsts, deg);
  k_scan1<<<nscan, SCAN_B, 0, stream>>>(deg, incl, bsum);
  k_scan2<<<1, 64, 0, stream>>>(bsum, nscan);
  k_scan3<<<nscan, SCAN_B, 0, stream>>>(incl, deg, bsum, off);
  k_scatter<<<(N_EDGES + 255) / 256, 256, 0, stream>>>(srcs, dsts, off, fill,
                                                       src_csr, ea, eac);
  dim3 wgrid(256, 2 * L_LAYERS);
  k_prepW<<<wgrid, 256, 0, stream>>>(Wl1, Wl2, Wt1, Wt2);
  k_init_h<<<N_NODES, 256, 0, stream>>>(x, Win, bin, hb0);

  const int lgrid = (N_NODES + FM - 1) / FM;
  bf16_t* hp = hb0;
  bf16_t* hn = hb1;
  for (int l = 0; l < L_LAYERS; ++l) {
    k_layer<<<lgrid, 512, 0, stream>>>(off, src_csr, eac, hp,
                                       We + (size_t)l * EF_DIM * H_DIM,
                                       be + l * H_DIM,
                                       Wt1 + (size_t)l * 65536,
                                       Wt2 + (size_t)l * 65536,
                                       bl1 + l * H_DIM, bl2 + l * H_DIM,
                                       bnw + l * H_DIM, bnb + l * H_DIM,
                                       bnm + l * H_DIM, bnv + l * H_DIM, hn);
    bf16_t* t = hp; hp = hn; hn = t;
  }
  // after 4 layers: final state is in hp (== hb0)

  float* out_g = out + 2048 + (size_t)G_GRAPHS * 64;  // edl(2048) + z(32768)
  k_pool<<<G_GRAPHS, 512, 0, stream>>>(batch, hp, g, out_g);
  k_tail<<<G_GRAPHS, 256, 0, stream>>>(g, gf, Wp1, bp1, Wp2, bp2, Wf1, bf1,
                                       Wf2, bf2, Wh, bh, out);
}

// Round 13
// 885.949 us; speedup vs baseline: 1.4227x; 1.4227x over previous
//
#include <hip/hip_runtime.h>
#include <math.h>

#define N_NODES 50000
#define N_EDGES 800000
#define G_GRAPHS 512
#define H_DIM 256
#define NF_DIM 32
#define EF_DIM 16
#define L_LAYERS 4
#define BN_EPS 1e-5f

typedef __bf16 bf16_t;
typedef __attribute__((ext_vector_type(8))) __bf16 bf16x8;
typedef __attribute__((ext_vector_type(4))) float f32x4;
typedef _Float16 f16_t;
typedef __attribute__((ext_vector_type(2))) _Float16 f16x2;
typedef __attribute__((ext_vector_type(8))) _Float16 f16x8;

union f16x8_pairs {
  f16x8 v;
  f16x2 p[4];
};

// ---------------- hb = bf16(x @ Win + bin) ---------------------------------
__global__ __launch_bounds__(256) void k_init_h(
    const float* __restrict__ x, const float* __restrict__ Win,
    const float* __restrict__ bin, bf16_t* __restrict__ hb) {
  int row = blockIdx.x;
  int c = threadIdx.x;
  __shared__ float xs[NF_DIM];
  if (threadIdx.x < NF_DIM) xs[threadIdx.x] = x[(size_t)row * NF_DIM + threadIdx.x];
  __syncthreads();
  float acc = bin[c];
#pragma unroll
  for (int k = 0; k < NF_DIM; ++k) acc += xs[k] * Win[k * H_DIM + c];
  hb[(size_t)row * H_DIM + c] = (bf16_t)acc;
}

// ---------------- weight transpose + bf16 cast (both W1,W2 in one grid) ----
__global__ __launch_bounds__(256) void k_prepW(
    const float* __restrict__ Wl1, const float* __restrict__ Wl2,
    bf16_t* __restrict__ Wt1, bf16_t* __restrict__ Wt2) {
  int n = blockIdx.x;
  int ly = blockIdx.y;  // 0..7
  int k = threadIdx.x;
  const float* W = (ly < L_LAYERS) ? Wl1 : Wl2;
  bf16_t* Wt = (ly < L_LAYERS) ? Wt1 : Wt2;
  int l = ly & 3;
  Wt[(size_t)l * 65536 + n * 256 + k] = (bf16_t)W[(size_t)l * 65536 + k * 256 + n];
}

// ---------------- CSR build ------------------------------------------------
__global__ __launch_bounds__(256) void k_deg(
    const int* __restrict__ dsts, int* __restrict__ deg) {
  int e = blockIdx.x * 256 + threadIdx.x;
  if (e < N_EDGES) atomicAdd(&deg[dsts[e]], 1);
}

#define SCAN_B 512
__global__ __launch_bounds__(SCAN_B) void k_scan1(
    const int* __restrict__ deg, int* __restrict__ incl, int* __restrict__ bsum) {
  __shared__ int s[SCAN_B];
  int gidx = blockIdx.x * SCAN_B + threadIdx.x;
  int v = (gidx < N_NODES) ? deg[gidx] : 0;
  s[threadIdx.x] = v;
  __syncthreads();
  for (int off = 1; off < SCAN_B; off <<= 1) {
    int t = (threadIdx.x >= off) ? s[threadIdx.x - off] : 0;
    __syncthreads();
    s[threadIdx.x] += t;
    __syncthreads();
  }
  if (gidx < N_NODES) incl[gidx] = s[threadIdx.x];
  if (threadIdx.x == SCAN_B - 1) bsum[blockIdx.x] = s[SCAN_B - 1];
}

__global__ void k_scan2(int* __restrict__ bsum, int nb) {
  if (threadIdx.x == 0 && blockIdx.x == 0) {
    int acc = 0;
    for (int i = 0; i < nb; ++i) { int t = bsum[i]; bsum[i] = acc; acc += t; }
  }
}

__global__ __launch_bounds__(SCAN_B) void k_scan3(
    const int* __restrict__ incl, const int* __restrict__ deg,
    const int* __restrict__ bsum, int* __restrict__ off) {
  int gidx = blockIdx.x * SCAN_B + threadIdx.x;
  if (gidx < N_NODES) off[gidx] = incl[gidx] - deg[gidx] + bsum[blockIdx.x];
  if (gidx == 0) off[N_NODES] = N_EDGES;
}

// scatter + direct ea->f16 reorder (no eid pass)
__global__ __launch_bounds__(256) void k_scatter(
    const int* __restrict__ srcs, const int* __restrict__ dsts,
    const int* __restrict__ off, int* __restrict__ fill,
    int* __restrict__ src_csr, const float* __restrict__ ea,
    f16_t* __restrict__ eac) {
  int e = blockIdx.x * 256 + threadIdx.x;
  if (e < N_EDGES) {
    int d = dsts[e];
    int pos = atomicAdd(&fill[d], 1);
    int idx = off[d] + pos;
    src_csr[idx] = srcs[e];
    const f32x4* p = (const f32x4*)(ea + (size_t)e * EF_DIM);
    f32x4 v0 = p[0], v1 = p[1], v2 = p[2], v3 = p[3];
    f16x8 o0, o1;
    o0[0] = (f16_t)v0.x; o0[1] = (f16_t)v0.y; o0[2] = (f16_t)v0.z; o0[3] = (f16_t)v0.w;
    o0[4] = (f16_t)v1.x; o0[5] = (f16_t)v1.y; o0[6] = (f16_t)v1.z; o0[7] = (f16_t)v1.w;
    o1[0] = (f16_t)v2.x; o1[1] = (f16_t)v2.y; o1[2] = (f16_t)v2.z; o1[3] = (f16_t)v2.w;
    o1[4] = (f16_t)v3.x; o1[5] = (f16_t)v3.y; o1[6] = (f16_t)v3.z; o1[7] = (f16_t)v3.w;
    f16x8* dst = (f16x8*)(eac + (size_t)idx * EF_DIM);
    dst[0] = o0;
    dst[1] = o1;
  }
}

// ---------------- aggregation: t0b = bf16(hb + sum relu(hb[src]+ea@We+be)) -
// 128 threads/block, thread owns cols (2c,2c+1); grid-stride ~4 nodes/block.
#define AGGR_GRID 12544

__device__ __forceinline__ void edge_dot2(const f16_t* __restrict__ eac,
                                          size_t i, const f16x2* __restrict__ w0,
                                          const f16x2* __restrict__ w1,
                                          float& m0, float& m1) {
  const f16x8* pp = (const f16x8*)(eac + i * EF_DIM);
  f16x8_pairs u0, u1;
  u0.v = pp[0];
  u1.v = pp[1];
#pragma unroll
  for (int j = 0; j < 4; ++j) {
    m0 = __builtin_amdgcn_fdot2(u0.p[j], w0[j], m0, false);
    m1 = __builtin_amdgcn_fdot2(u0.p[j], w1[j], m1, false);
  }
#pragma unroll
  for (int j = 0; j < 4; ++j) {
    m0 = __builtin_amdgcn_fdot2(u1.p[j], w0[j + 4], m0, false);
    m1 = __builtin_amdgcn_fdot2(u1.p[j], w1[j + 4], m1, false);
  }
}

__global__ __launch_bounds__(128) void k_aggr(
    const int* __restrict__ off, const int* __restrict__ src_csr,
    const f16_t* __restrict__ eac, const bf16_t* __restrict__ hb,
    const float* __restrict__ We, const float* __restrict__ be,
    bf16_t* __restrict__ t0b) {
  const int tid = threadIdx.x;       // 0..127
  const int c0 = tid * 2;
  f16x2 w0[8], w1[8];
#pragma unroll
  for (int j = 0; j < 8; ++j) {
    f16x2 t0, t1;
    t0[0] = (f16_t)We[(2 * j) * H_DIM + c0];
    t0[1] = (f16_t)We[(2 * j + 1) * H_DIM + c0];
    t1[0] = (f16_t)We[(2 * j) * H_DIM + c0 + 1];
    t1[1] = (f16_t)We[(2 * j + 1) * H_DIM + c0 + 1];
    w0[j] = t0;
    w1[j] = t1;
  }
  const float be0 = be[c0], be1 = be[c0 + 1];
  const unsigned* __restrict__ hb32 = (const unsigned*)hb;
  for (int n = blockIdx.x; n < N_NODES; n += AGGR_GRID) {
    const int s0 = off[n], s1 = off[n + 1];
    float acc0 = 0.f, acc1 = 0.f;
    int i = s0;
    for (; i + 4 <= s1; i += 4) {
      int sA = src_csr[i], sB = src_csr[i + 1], sC = src_csr[i + 2], sD = src_csr[i + 3];
      unsigned uA = hb32[(unsigned)sA * 128u + tid];
      unsigned uB = hb32[(unsigned)sB * 128u + tid];
      unsigned uC = hb32[(unsigned)sC * 128u + tid];
      unsigned uD = hb32[(unsigned)sD * 128u + tid];
      float mA0 = be0, mA1 = be1, mB0 = be0, mB1 = be1;
      float mC0 = be0, mC1 = be1, mD0 = be0, mD1 = be1;
      edge_dot2(eac, (size_t)i, w0, w1, mA0, mA1);
      edge_dot2(eac, (size_t)i + 1, w0, w1, mB0, mB1);
      edge_dot2(eac, (size_t)i + 2, w0, w1, mC0, mC1);
      edge_dot2(eac, (size_t)i + 3, w0, w1, mD0, mD1);
      acc0 += fmaxf(mA0 + __uint_as_float(uA << 16), 0.f) +
              fmaxf(mB0 + __uint_as_float(uB << 16), 0.f) +
              fmaxf(mC0 + __uint_as_float(uC << 16), 0.f) +
              fmaxf(mD0 + __uint_as_float(uD << 16), 0.f);
      acc1 += fmaxf(mA1 + __uint_as_float(uA & 0xFFFF0000u), 0.f) +
              fmaxf(mB1 + __uint_as_float(uB & 0xFFFF0000u), 0.f) +
              fmaxf(mC1 + __uint_as_float(uC & 0xFFFF0000u), 0.f) +
              fmaxf(mD1 + __uint_as_float(uD & 0xFFFF0000u), 0.f);
    }
    for (; i < s1; ++i) {
      int s = src_csr[i];
      unsigned u = hb32[(unsigned)s * 128u + tid];
      float m0 = be0, m1 = be1;
      edge_dot2(eac, (size_t)i, w0, w1, m0, m1);
      acc0 += fmaxf(m0 + __uint_as_float(u << 16), 0.f);
      acc1 += fmaxf(m1 + __uint_as_float(u & 0xFFFF0000u), 0.f);
    }
    unsigned hu = hb32[(size_t)n * 128 + tid];
    float h0 = __uint_as_float(hu << 16);
    float h1 = __uint_as_float(hu & 0xFFFF0000u);
    union { bf16_t b[2]; unsigned u; } pk;
    pk.b[0] = (bf16_t)(h0 + acc0);
    pk.b[1] = (bf16_t)(h1 + acc1);
    ((unsigned*)t0b)[(size_t)n * 128 + tid] = pk.u;
  }
}

// ---------------- fused layer MLP: hb += relu(bn(relu(t0@W1+b1)@W2+b2)) ----
// 64 rows/block, 512 threads / 8 waves (each 32 rows x 64 cols); As
// double-buffered; B-frags direct from L2-resident weights; t1 in LDS.
#define FM 64
#define LSTR 40    // bf16 elems per LDS k-row (32 + 8 pad)
#define T1STR 264  // bf16 elems per t1 row (256 + 8 pad)

__global__ __launch_bounds__(512) void k_mlp(
    const bf16_t* __restrict__ t0b, const bf16_t* __restrict__ W1t,
    const bf16_t* __restrict__ W2t, const float* __restrict__ b1,
    const float* __restrict__ b2, const float* __restrict__ bnw,
    const float* __restrict__ bnb, const float* __restrict__ bnm,
    const float* __restrict__ bnv, bf16_t* __restrict__ hb) {
  __shared__ bf16_t As[2][FM * LSTR];
  __shared__ bf16_t T1[FM * T1STR];
  const int tid = threadIdx.x;
  const int bm = blockIdx.x * FM;
  const int lane = tid & 63;
  const int wv = tid >> 6;         // 0..7
  const int wm = (wv & 1) * 32;    // 32-row group
  const int wn = (wv >> 1) * 64;   // 64-col group
  const int l15 = lane & 15;
  const int kg = lane >> 4;
  const bool stager = tid < 256;
  const int arow = (tid & 255) >> 2, ach = (tid & 3) * 8;  // A staging coords
  f32x4 acc[2][4];

  // ---------- GEMM1: t1 = relu(t0 @ W1 + b1), result -> LDS T1 ----------
#pragma unroll
  for (int m = 0; m < 2; ++m)
#pragma unroll
    for (int n = 0; n < 4; ++n) acc[m][n] = (f32x4){0.f, 0.f, 0.f, 0.f};
  if (stager) {
    int grow = bm + arow;
    f32x4 v = {0.f, 0.f, 0.f, 0.f};
    if (grow < N_NODES) v = *(const f32x4*)&t0b[(size_t)grow * H_DIM + ach];
    *(f32x4*)&As[0][arow * LSTR + ach] = v;
  }
  __syncthreads();
  int p = 0;
  for (int ks = 0; ks < 8; ++ks) {
    const int k0 = ks * 32;
    bf16x8 af[2], bfr[4];
#pragma unroll
    for (int m = 0; m < 2; ++m)
      af[m] = *(const bf16x8*)&As[p][(wm + m * 16 + l15) * LSTR + kg * 8];
    if (ks < 7 && stager) {
      int grow = bm + arow;
      f32x4 v = {0.f, 0.f, 0.f, 0.f};
      if (grow < N_NODES)
        v = *(const f32x4*)&t0b[(size_t)grow * H_DIM + k0 + 32 + ach];
      *(f32x4*)&As[p ^ 1][arow * LSTR + ach] = v;
    }
#pragma unroll
    for (int n = 0; n < 4; ++n)
      bfr[n] = *(const bf16x8*)&W1t[(size_t)(wn + n * 16 + l15) * H_DIM + k0 + kg * 8];
#pragma unroll
    for (int m = 0; m < 2; ++m)
#pragma unroll
      for (int n = 0; n < 4; ++n)
        acc[m][n] =
            __builtin_amdgcn_mfma_f32_16x16x32_bf16(af[m], bfr[n], acc[m][n], 0, 0, 0);
    __syncthreads();
    p ^= 1;
  }
#pragma unroll
  for (int m = 0; m < 2; ++m) {
    int rl0 = wm + m * 16 + kg * 4;
#pragma unroll
    for (int n = 0; n < 4; ++n) {
      int col = wn + n * 16 + l15;
      float bi = b1[col];
#pragma unroll
      for (int r = 0; r < 4; ++r)
        T1[(rl0 + r) * T1STR + col] = (bf16_t)fmaxf(acc[m][n][r] + bi, 0.f);
    }
  }
  __syncthreads();

  // ---------- GEMM2: v = t1 @ W2 + b2; hb += relu(bn(v)) (no barriers) -----
#pragma unroll
  for (int m = 0; m < 2; ++m)
#pragma unroll
    for (int n = 0; n < 4; ++n) acc[m][n] = (f32x4){0.f, 0.f, 0.f, 0.f};
  for (int ks = 0; ks < 8; ++ks) {
    const int k0 = ks * 32;
    bf16x8 af[2], bfr[4];
#pragma unroll
    for (int m = 0; m < 2; ++m)
      af[m] = *(const bf16x8*)&T1[(wm + m * 16 + l15) * T1STR + k0 + kg * 8];
#pragma unroll
    for (int n = 0; n < 4; ++n)
      bfr[n] = *(const bf16x8*)&W2t[(size_t)(wn + n * 16 + l15) * H_DIM + k0 + kg * 8];
#pragma unroll
    for (int m = 0; m < 2; ++m)
#pragma unroll
      for (int n = 0; n < 4; ++n)
        acc[m][n] =
            __builtin_amdgcn_mfma_f32_16x16x32_bf16(af[m], bfr[n], acc[m][n], 0, 0, 0);
  }
#pragma unroll
  for (int m = 0; m < 2; ++m) {
    int row0 = bm + wm + m * 16 + kg * 4;
#pragma unroll
    for (int n = 0; n < 4; ++n) {
      int col = wn + n * 16 + l15;
      float bi = b2[col];
      float sc = bnw[col] * rsqrtf(bnv[col] + BN_EPS);
      float mu = bnm[col];
      float sb = bnb[col];
#pragma unroll
      for (int r = 0; r < 4; ++r) {
        int rr = row0 + r;
        if (rr < N_NODES) {
          float v = (acc[m][n][r] + bi - mu) * sc + sb;
          size_t o = (size_t)rr * H_DIM + col;
          float old = (float)hb[o];
          hb[o] = (bf16_t)(old + fmaxf(v, 0.f));
        }
      }
    }
  }
}

// ---------------- fused pool + heads: one block per graph ------------------
__device__ __forceinline__ float softplusf(float x) {
  return fmaxf(x, 0.f) + log1pf(expf(-fabsf(x)));
}

__global__ __launch_bounds__(512) void k_pooltail(
    const int* __restrict__ batch, const bf16_t* __restrict__ hb,
    const float* __restrict__ gf,
    const float* __restrict__ Wp1, const float* __restrict__ bp1,
    const float* __restrict__ Wp2, const float* __restrict__ bp2,
    const float* __restrict__ Wf1, const float* __restrict__ bf1,
    const float* __restrict__ Wf2, const float* __restrict__ bf2,
    const float* __restrict__ Wh, const float* __restrict__ bh,
    float* __restrict__ out, float* __restrict__ out_g) {
  int gid = blockIdx.x;
  int tid = threadIdx.x;
  __shared__ float red[4][H_DIM];
  __shared__ float gc[H_DIM + NF_DIM];
  __shared__ float z1[128];
  __shared__ float q1[H_DIM];
  __shared__ float q2[128];

  // ---- pool phase: g = sum over nodes of this graph (batch sorted) ----
  {
    int cp = tid & 127;   // col pair
    int rl = tid >> 7;    // 0..3
    int lo = 0, hi = N_NODES;
    while (lo < hi) { int mid = (lo + hi) >> 1; if (batch[mid] < gid) lo = mid + 1; else hi = mid; }
    int start = lo;
    int lo2 = start, hi2 = N_NODES;
    while (lo2 < hi2) { int mid = (lo2 + hi2) >> 1; if (batch[mid] < gid + 1) lo2 = mid + 1; else hi2 = mid; }
    int end = lo2;
    const unsigned* hb32 = (const unsigned*)hb;
    float a0 = 0.f, a1 = 0.f;
    for (int n = start + rl; n < end; n += 4) {
      unsigned u = hb32[(size_t)n * 128 + cp];
      a0 += __uint_as_float(u << 16);
      a1 += __uint_as_float(u & 0xFFFF0000u);
    }
    red[rl][2 * cp] = a0;
    red[rl][2 * cp + 1] = a1;
    __syncthreads();
    if (rl == 0) {
      float s0 = red[0][2 * cp] + red[1][2 * cp] + red[2][2 * cp] + red[3][2 * cp];
      float s1 = red[0][2 * cp + 1] + red[1][2 * cp + 1] + red[2][2 * cp + 1] + red[3][2 * cp + 1];
      gc[2 * cp] = s0;
      gc[2 * cp + 1] = s1;
      out_g[(size_t)gid * H_DIM + 2 * cp] = s0;
      out_g[(size_t)gid * H_DIM + 2 * cp + 1] = s1;
    }
    if (tid < NF_DIM) gc[H_DIM + tid] = gf[(size_t)gid * NF_DIM + tid];
  }
  __syncthreads();

  // ---- tail phase (threads < 256 do the col-parallel MLPs) ----
  int c = tid;
  if (c < 256) {
    float aq = bf1[c];
#pragma unroll 8
    for (int k = 0; k < H_DIM + NF_DIM; ++k) aq += gc[k] * Wf1[k * H_DIM + c];
    if (c < 128) {
      float a = bp1[c];
#pragma unroll 8
      for (int k = 0; k < H_DIM; ++k) a += gc[k] * Wp1[k * 128 + c];
      z1[c] = fmaxf(a, 0.f);
    }
    q1[c] = fmaxf(aq, 0.f);
  }
  __syncthreads();
  if (c < 64) {
    float a = bp2[c];
#pragma unroll 8
    for (int k = 0; k < 128; ++k) a += z1[k] * Wp2[k * 64 + c];
    float ss = a * a;
#pragma unroll
    for (int o = 32; o; o >>= 1) ss += __shfl_xor(ss, o);
    float nrm = fmaxf(sqrtf(ss), 1e-12f);
    out[2048 + (size_t)gid * 64 + c] = a / nrm;
  }
  if (c >= 64 && c < 192) {
    int cc = c - 64;
    float a = bf2[cc];
#pragma unroll 8
    for (int k = 0; k < H_DIM; ++k) a += q1[k] * Wf2[k * 128 + cc];
    q2[cc] = fmaxf(a, 0.f);
  }
  __syncthreads();
  if (c < 4) {
    float a = bh[c];
#pragma unroll 8
    for (int k = 0; k < 128; ++k) a += q2[k] * Wh[k * 4 + c];
    float v;
    if (c == 0) v = a;
    else if (c == 2) v = softplusf(a) + 1.f + 1e-6f;
    else v = softplusf(a) + 1e-6f;
    out[(size_t)gid * 4 + c] = v;
  }
}

extern "C" void kernel_launch(void* const* d_in, const int* in_sizes, int n_in,
                              void* d_out, int out_size, void* d_ws, size_t ws_size,
                              hipStream_t stream) {
  const float* x     = (const float*)d_in[0];
  const int*   ei    = (const int*)d_in[1];
  const float* ea    = (const float*)d_in[2];
  const int*   batch = (const int*)d_in[3];
  const float* gf    = (const float*)d_in[4];
  const float* Win   = (const float*)d_in[5];
  const float* bin   = (const float*)d_in[6];
  const float* We    = (const float*)d_in[7];
  const float* be    = (const float*)d_in[8];
  const float* Wl1   = (const float*)d_in[9];
  const float* bl1   = (const float*)d_in[10];
  const float* Wl2   = (const float*)d_in[11];
  const float* bl2   = (const float*)d_in[12];
  const float* bnw   = (const float*)d_in[13];
  const float* bnb   = (const float*)d_in[14];
  const float* bnm   = (const float*)d_in[15];
  const float* bnv   = (const float*)d_in[16];
  const float* Wp1   = (const float*)d_in[17];
  const float* bp1   = (const float*)d_in[18];
  const float* Wp2   = (const float*)d_in[19];
  const float* bp2   = (const float*)d_in[20];
  const float* Wf1   = (const float*)d_in[21];
  const float* bf1   = (const float*)d_in[22];
  const float* Wf2   = (const float*)d_in[23];
  const float* bf2   = (const float*)d_in[24];
  const float* Wh    = (const float*)d_in[25];
  const float* bh    = (const float*)d_in[26];
  float* out = (float*)d_out;

  const int* srcs = ei;
  const int* dsts = ei + N_EDGES;

  const size_t NH = (size_t)N_NODES * H_DIM;
  f16_t* eac = (f16_t*)d_ws;                      // N_EDGES*16 f16
  bf16_t* t0b = (bf16_t*)(eac + (size_t)N_EDGES * EF_DIM);
  bf16_t* hb  = t0b + NH;
  bf16_t* Wt1 = hb + NH;                          // 4*65536
  bf16_t* Wt2 = Wt1 + (size_t)L_LAYERS * 65536;
  int* deg  = (int*)(Wt2 + (size_t)L_LAYERS * 65536);
  int* fill = deg + N_NODES;
  int* incl = fill + N_NODES;
  int* off  = incl + N_NODES;       // N_NODES + 1
  int* bsum = off + N_NODES + 1;    // 128
  int* src_csr = bsum + 128;        // N_EDGES

  // ---- one-time prep: CSR build (+ea reorder fused) + weight cast + proj --
  hipMemsetAsync(deg, 0, N_NODES * sizeof(int), stream);
  hipMemsetAsync(fill, 0, N_NODES * sizeof(int), stream);
  const int nscan = (N_NODES + SCAN_B - 1) / SCAN_B;
  k_deg<<<(N_EDGES + 255) / 256, 256, 0, stream>>>(dsts, deg);
  k_scan1<<<nscan, SCAN_B, 0, stream>>>(deg, incl, bsum);
  k_scan2<<<1, 64, 0, stream>>>(bsum, nscan);
  k_scan3<<<nscan, SCAN_B, 0, stream>>>(incl, deg, bsum, off);
  k_scatter<<<(N_EDGES + 255) / 256, 256, 0, stream>>>(srcs, dsts, off, fill,
                                                       src_csr, ea, eac);
  dim3 wgrid(256, 2 * L_LAYERS);
  k_prepW<<<wgrid, 256, 0, stream>>>(Wl1, Wl2, Wt1, Wt2);
  k_init_h<<<N_NODES, 256, 0, stream>>>(x, Win, bin, hb);

  const int mlpg = (N_NODES + FM - 1) / FM;
  for (int l = 0; l < L_LAYERS; ++l) {
    k_aggr<<<AGGR_GRID, 128, 0, stream>>>(off, src_csr, eac, hb,
                                          We + (size_t)l * EF_DIM * H_DIM,
                                          be + l * H_DIM, t0b);
    k_mlp<<<mlpg, 512, 0, stream>>>(t0b, Wt1 + (size_t)l * 65536,
                                    Wt2 + (size_t)l * 65536, bl1 + l * H_DIM,
                                    bl2 + l * H_DIM, bnw + l * H_DIM,
                                    bnb + l * H_DIM, bnm + l * H_DIM,
                                    bnv + l * H_DIM, hb);
  }

  float* out_g = out + 2048 + (size_t)G_GRAPHS * 64;  // edl(2048) + z(32768)
  k_pooltail<<<G_GRAPHS, 512, 0, stream>>>(batch, hb, gf, Wp1, bp1, Wp2, bp2,
                                           Wf1, bf1, Wf2, bf2, Wh, bh, out, out_g);
}